// Round 3
// baseline (1747.074 us; speedup 1.0000x reference)
//
#include <hip/hip_runtime.h>

#define NB 64
#define NN 128
#define ME 32
#define DI 64
#define ROWD 130   // padded row length in doubles (65 double2 groups)
#define ROW2 65

// SGPR broadcast of lane `lane`'s value. CONTRACT: source computed by all 64 lanes.
__device__ __forceinline__ double rld(double v, int lane) {
  union { double d; unsigned long long u; } c; c.d = v;
  unsigned lo = (unsigned)c.u, hi = (unsigned)(c.u >> 32);
  lo = (unsigned)__builtin_amdgcn_readlane((int)lo, lane);
  hi = (unsigned)__builtin_amdgcn_readlane((int)hi, lane);
  c.u = (((unsigned long long)hi) << 32) | lo;
  return c.d;
}

__global__ __launch_bounds__(256, 1) void altdiff_kernel(
    const float* __restrict__ Qg, const float* __restrict__ qg,
    const float* __restrict__ Gg, const float* __restrict__ hg,
    const float* __restrict__ Ag, const float* __restrict__ bg,
    float* __restrict__ out)
{
  extern __shared__ double ldsd[];   // 128*130 doubles = 133120 B (dynamic)
  double2* lds2 = (double2*)ldsd;

  const int bidx = blockIdx.x;
  const int tid  = threadIdx.x;

  const float* Qb = Qg + (size_t)bidx * NN * NN;
  const float* Ab = Ag + (size_t)bidx * ME * NN;
  const float* Gb = Gg + (size_t)bidx * DI * NN;
  const float* qb = qg + (size_t)bidx * NN;
  const float* hb = hg + (size_t)bidx * DI;
  const float* bv = bg + (size_t)bidx * ME;

  // ---------------- Phase 1: M = Q + A^T A + G^T G in f64 -> LDS rows of 130 doubles ----------------
  {
    const int r = tid >> 4, c = tid & 15;   // 8x8 tile at rows 8r.., cols 8c..
    double acc[8][8];
    const float4* Q4 = (const float4*)Qb;
#pragma unroll
    for (int rr = 0; rr < 8; ++rr) {
      float4 q0 = Q4[((8*r+rr) << 5) + 2*c];
      float4 q1 = Q4[((8*r+rr) << 5) + 2*c + 1];
      acc[rr][0]=(double)q0.x; acc[rr][1]=(double)q0.y; acc[rr][2]=(double)q0.z; acc[rr][3]=(double)q0.w;
      acc[rr][4]=(double)q1.x; acc[rr][5]=(double)q1.y; acc[rr][6]=(double)q1.z; acc[rr][7]=(double)q1.w;
    }
    const float4* A4 = (const float4*)Ab;
    for (int m = 0; m < ME; ++m) {
      float4 u0 = A4[(m << 5) + 2*r], u1 = A4[(m << 5) + 2*r + 1];
      float4 v0 = A4[(m << 5) + 2*c], v1 = A4[(m << 5) + 2*c + 1];
      double uu[8] = {(double)u0.x,(double)u0.y,(double)u0.z,(double)u0.w,
                      (double)u1.x,(double)u1.y,(double)u1.z,(double)u1.w};
      double vv[8] = {(double)v0.x,(double)v0.y,(double)v0.z,(double)v0.w,
                      (double)v1.x,(double)v1.y,(double)v1.z,(double)v1.w};
#pragma unroll
      for (int rr = 0; rr < 8; ++rr)
#pragma unroll
        for (int cc = 0; cc < 8; ++cc)
          acc[rr][cc] = fma(uu[rr], vv[cc], acc[rr][cc]);
    }
    const float4* G4 = (const float4*)Gb;
    for (int d = 0; d < DI; ++d) {
      float4 u0 = G4[(d << 5) + 2*r], u1 = G4[(d << 5) + 2*r + 1];
      float4 v0 = G4[(d << 5) + 2*c], v1 = G4[(d << 5) + 2*c + 1];
      double uu[8] = {(double)u0.x,(double)u0.y,(double)u0.z,(double)u0.w,
                      (double)u1.x,(double)u1.y,(double)u1.z,(double)u1.w};
      double vv[8] = {(double)v0.x,(double)v0.y,(double)v0.z,(double)v0.w,
                      (double)v1.x,(double)v1.y,(double)v1.z,(double)v1.w};
#pragma unroll
      for (int rr = 0; rr < 8; ++rr)
#pragma unroll
        for (int cc = 0; cc < 8; ++cc)
          acc[rr][cc] = fma(uu[rr], vv[cc], acc[rr][cc]);
    }
#pragma unroll
    for (int rr = 0; rr < 8; ++rr) {
      int ir = 8*r + rr;
#pragma unroll
      for (int t = 0; t < 4; ++t)
        lds2[ir*ROW2 + 4*c + t] = make_double2(acc[rr][2*t], acc[rr][2*t+1]);
    }
  }
  __syncthreads();

  // ---------------- Phase 2: f64 in-place sweep of all 128 pivots -> LDS holds R = -M^{-1} ----------------
  {
    const int i = tid >> 1, h = tid & 1;   // thread owns row i, 64-col half h
    for (int k = 0; k < NN; ++k) {
      const int kh = k >> 6, kg = (k >> 1) & 31, kc = k & 1;
      const double dkk  = ldsd[k*ROWD + k];          // same-address broadcast
      const double rcpd = 1.0 / dkk;                 // pivots >= 1 (M >= I), safe
      const double cv   = ldsd[i*ROWD + k] * rcpd;   // this row's divided col-k value
      __syncthreads();                               // all reads done before any write
      const double2* krow  = lds2 + k*ROW2;
      double2*       myrow = lds2 + i*ROW2;
      double2 rv[32];
      if (i == k) {
        // divide pivot row into registers (deferred store), set (k,k) = -1/d
#pragma unroll
        for (int jj = 0; jj < 32; ++jj) {
          double2 v = myrow[(h << 5) | jj];
          v.x *= rcpd; v.y *= rcpd;
          if (jj == kg && h == kh) { if (kc == 0) v.x = -rcpd; else v.y = -rcpd; }
          rv[jj] = v;
        }
      } else {
        // trailing update: M[i][j] -= cv * M[k][j]  (col k masked to 0, then set to cv)
#pragma unroll
        for (int jj = 0; jj < 32; ++jj) {
          double2 rk = krow[(h << 5) | jj];
          if (jj == kg && h == kh) { if (kc == 0) rk.x = 0.0; else rk.y = 0.0; }
          double2 ow = myrow[(h << 5) | jj];
          ow.x = fma(-cv, rk.x, ow.x);
          ow.y = fma(-cv, rk.y, ow.y);
          if (jj == kg && h == kh) { if (kc == 0) ow.x = cv; else ow.y = cv; }
          myrow[(h << 5) | jj] = ow;
        }
      }
      __syncthreads();
      if (i == k) {
#pragma unroll
        for (int jj = 0; jj < 32; ++jj)
          myrow[(h << 5) | jj] = rv[jj];
      }
      __syncthreads();
    }
  }

  // ---------------- Phase 3: copy R to registers, restage LDS, iterate (f64) ----------------
  const int w  = tid >> 6;            // wave id 0..3
  const int l  = tid & 63;            // lane
  const int hB = w >> 1;              // R column-half owned for step B
  const int iB = ((w & 1) << 6) | l;  // row index 0..127 owned for steps A/B

  double Rr[64];                      // R[iB][64*hB .. 64*hB+63]
#pragma unroll
  for (int j = 0; j < 64; ++j)
    Rr[j] = ldsd[iB*ROWD + (hB << 6) + j];
  __syncthreads();    // LDS now reusable

  // Phase-3 LDS layout. As: f32 [32][132] in bytes [0,16896) = doubles [0,2112).
  float*  As   = (float*)ldsd;        // A rows staged f32
  double* rhsa = ldsd + 2112;         // [128]
  double* rhsg = ldsd + 2240;         // [128]
  double* xpa  = ldsd + 2368;         // [128] x partial (half 0)
  double* xpb  = ldsd + 2496;         // [128] x partial (half 1)
  double* Gxq  = ldsd + 2624;         // [128] Gx partials (q*64+d)
  double* Axq  = ldsd + 2752;         // [64]  Ax partials (q*32+m)
  double* snu  = ldsd + 2816;         // [64]  nu + sk
  double* lmb  = ldsd + 2880;         // [32]  lambda
  int*   flagp = (int*)(ldsd + 2912);

  for (int idx = tid; idx < ME * NN; idx += 256) {
    int m = idx >> 7, n = idx & 127;
    As[m * 132 + n] = Ab[idx];
  }
  if (tid < DI) snu[tid] = 0.0;
  else if (tid < DI + ME) lmb[tid - DI] = 0.0;

  // per-wave register matrices (f32 — inputs are exact f32, cast to f64 at use)
  float4 MatA[16];    // waves 0/1: G[l][64w..]   ; waves 2/3: G^T[iB][0..63]
  float4 MatB[8];     // waves 0/1: A^T[iB][0..31]; waves 2/3: unused
  double c_r = 0.0, h_r = 0.0, b_r = 0.0, qr0 = 0.0, qr1 = 0.0;
  double nu_r = 0.0, lamb_r = 0.0;
  double res_prev = 1000.0, res_cur = -100.0;

  if (w < 2) {
    const float4* G4 = (const float4*)Gb;
#pragma unroll
    for (int j4 = 0; j4 < 16; ++j4) MatA[j4] = G4[(l << 5) + (w << 4) + j4];
#pragma unroll
    for (int m4 = 0; m4 < 8; ++m4)
      MatB[m4] = make_float4(Ab[(4*m4+0)*NN + iB], Ab[(4*m4+1)*NN + iB],
                             Ab[(4*m4+2)*NN + iB], Ab[(4*m4+3)*NN + iB]);
    if (w == 0) h_r = (double)hb[l];
    if (w == 1 && l < ME) b_r = (double)bv[l];
  } else {
#pragma unroll
    for (int d4 = 0; d4 < 16; ++d4)
      MatA[d4] = make_float4(Gb[(4*d4+0)*NN + iB], Gb[(4*d4+1)*NN + iB],
                             Gb[(4*d4+2)*NN + iB], Gb[(4*d4+3)*NN + iB]);
    if (w == 2) { qr0 = (double)qb[l]; qr1 = (double)qb[64 + l]; }
  }
  __syncthreads();

  // c = q - A^T b - G^T h   (G^T h by waves 2/3 into rhsg; then c_r held by waves 0/1)
  if (w >= 2) {
    double hreg = (double)hb[l];
    double s0 = 0, s1 = 0, s2 = 0, s3 = 0;
#pragma unroll
    for (int d4 = 0; d4 < 16; ++d4) {
      float4 g = MatA[d4];
      s0 = fma((double)g.x, rld(hreg, 4*d4+0), s0);
      s1 = fma((double)g.y, rld(hreg, 4*d4+1), s1);
      s2 = fma((double)g.z, rld(hreg, 4*d4+2), s2);
      s3 = fma((double)g.w, rld(hreg, 4*d4+3), s3);
    }
    rhsg[iB] = (s0 + s1) + (s2 + s3);
  }
  __syncthreads();
  if (w < 2) {
    double breg = (double)bv[l & 31];
    double s0 = 0, s1 = 0, s2 = 0, s3 = 0;
#pragma unroll
    for (int m4 = 0; m4 < 8; ++m4) {
      float4 a = MatB[m4];
      s0 = fma((double)a.x, rld(breg, 4*m4+0), s0);
      s1 = fma((double)a.y, rld(breg, 4*m4+1), s1);
      s2 = fma((double)a.z, rld(breg, 4*m4+2), s2);
      s3 = fma((double)a.w, rld(breg, 4*m4+3), s3);
    }
    c_r = (double)qb[iB] - ((s0 + s1) + (s2 + s3)) - rhsg[iB];
  }
  __syncthreads();

  // ---------------- ADMM iteration (f64, matches reference trajectory) ----------------
  for (int it = 0; it < 5000; ++it) {
    // A: rhs = c + A^T lamb + G^T (nu + sk)
    if (w < 2) {
      double lreg = lmb[l & 31];
      double s0 = 0, s1 = 0, s2 = 0, s3 = 0;
#pragma unroll
      for (int m4 = 0; m4 < 8; ++m4) {
        float4 a = MatB[m4];
        s0 = fma((double)a.x, rld(lreg, 4*m4+0), s0);
        s1 = fma((double)a.y, rld(lreg, 4*m4+1), s1);
        s2 = fma((double)a.z, rld(lreg, 4*m4+2), s2);
        s3 = fma((double)a.w, rld(lreg, 4*m4+3), s3);
      }
      rhsa[iB] = c_r + (s0 + s1) + (s2 + s3);
    } else {
      double sreg = snu[l];
      double s0 = 0, s1 = 0, s2 = 0, s3 = 0;
#pragma unroll
      for (int d4 = 0; d4 < 16; ++d4) {
        float4 g = MatA[d4];
        s0 = fma((double)g.x, rld(sreg, 4*d4+0), s0);
        s1 = fma((double)g.y, rld(sreg, 4*d4+1), s1);
        s2 = fma((double)g.z, rld(sreg, 4*d4+2), s2);
        s3 = fma((double)g.w, rld(sreg, 4*d4+3), s3);
      }
      rhsg[iB] = (s0 + s1) + (s2 + s3);
    }
    __syncthreads();
    // B: x = R * rhs   (each thread: 64-col half of one row)
    {
      double rreg = rhsa[(hB << 6) | l] + rhsg[(hB << 6) | l];
      double s0 = 0, s1 = 0, s2 = 0, s3 = 0;
#pragma unroll
      for (int j4 = 0; j4 < 16; ++j4) {
        s0 = fma(Rr[4*j4+0], rld(rreg, 4*j4+0), s0);
        s1 = fma(Rr[4*j4+1], rld(rreg, 4*j4+1), s1);
        s2 = fma(Rr[4*j4+2], rld(rreg, 4*j4+2), s2);
        s3 = fma(Rr[4*j4+3], rld(rreg, 4*j4+3), s3);
      }
      (hB ? xpb : xpa)[iB] = (s0 + s1) + (s2 + s3);
    }
    __syncthreads();
    // C: Gx (waves 0/1, reg G-rows) and Ax (waves 2/3, LDS A-rows).
    // Every readlane source is computed by ALL lanes (no divergence upstream).
    if (w < 2) {
      const int q = w;
      double xreg = xpa[(q << 6) | l] + xpb[(q << 6) | l];
      double s0 = 0, s1 = 0, s2 = 0, s3 = 0;
#pragma unroll
      for (int j4 = 0; j4 < 16; ++j4) {
        float4 g = MatA[j4];
        s0 = fma((double)g.x, rld(xreg, 4*j4+0), s0);
        s1 = fma((double)g.y, rld(xreg, 4*j4+1), s1);
        s2 = fma((double)g.z, rld(xreg, 4*j4+2), s2);
        s3 = fma((double)g.w, rld(xreg, 4*j4+3), s3);
      }
      Gxq[(q << 6) | l] = (s0 + s1) + (s2 + s3);
    } else {
      const int q = w - 2;
      double xreg = xpa[(q << 6) | l] + xpb[(q << 6) | l];
      const float4* As4 = (const float4*)As;
      const int mrow = l & 31;       // lanes 32..63 duplicate rows 0..31 (broadcast reads)
      double s0 = 0, s1 = 0, s2 = 0, s3 = 0;
#pragma unroll
      for (int j4 = 0; j4 < 16; ++j4) {
        float4 a = As4[mrow*33 + (q << 4) + j4];
        s0 = fma((double)a.x, rld(xreg, 4*j4+0), s0);
        s1 = fma((double)a.y, rld(xreg, 4*j4+1), s1);
        s2 = fma((double)a.z, rld(xreg, 4*j4+2), s2);
        s3 = fma((double)a.w, rld(xreg, 4*j4+3), s3);
      }
      if (l < ME) Axq[(q << 5) | l] = (s0 + s1) + (s2 + s3);
    }
    __syncthreads();
    // D: state updates (waves 0/1)  |  E: objective + convergence (wave 2)
    if (w == 0) {
      double Gx = Gxq[l] + Gxq[64 + l];
      double sk = fmax(0.0, -nu_r - Gx + h_r);
      nu_r = nu_r + Gx + sk - h_r;
      snu[l] = nu_r + sk;
    } else if (w == 1) {
      if (l < ME) {
        double Ax = Axq[l] + Axq[32 + l];
        lamb_r = lamb_r + Ax - b_r;
        lmb[l] = lamb_r;
      }
    } else if (w == 2) {
      double x0 = xpa[l] + xpb[l];
      double x1 = xpa[64 + l] + xpb[64 + l];
      double r0 = rhsa[l] + rhsg[l];
      double r1 = rhsa[64 + l] + rhsg[64 + l];
      double Gx = Gxq[l] + Gxq[64 + l];
      // obj = -0.5*(x.rhs + |Gx|^2 + |Ax|^2) + q.x ; exact since R is f64-accurate (x'Mx = -x.rhs)
      double t = -0.5 * (x0*r0 + x1*r1 + Gx*Gx) + qr0*x0 + qr1*x1;
      if (l < ME) { double Ax = Axq[l] + Axq[32 + l]; t -= 0.5 * Ax * Ax; }
#pragma unroll
      for (int off = 32; off >= 1; off >>= 1) t += __shfl_xor(t, off);
      if (l == 0) {
        res_prev = res_cur; res_cur = t;
        double rel = fabs((res_cur - res_prev) / res_prev);
        *flagp = (rel <= 1e-5) ? 1 : 0;
      }
    }
    __syncthreads();
    if (*flagp) break;
  }

  if (tid < NN) out[(size_t)bidx * NN + tid] = (float)(xpa[tid] + xpb[tid]);
}

extern "C" void kernel_launch(void* const* d_in, const int* in_sizes, int n_in,
                              void* d_out, int out_size, void* d_ws, size_t ws_size,
                              hipStream_t stream) {
  (void)in_sizes; (void)n_in; (void)out_size; (void)d_ws; (void)ws_size;
  const float* Q = (const float*)d_in[0];
  const float* q = (const float*)d_in[1];
  const float* G = (const float*)d_in[2];
  const float* h = (const float*)d_in[3];
  const float* A = (const float*)d_in[4];
  const float* b = (const float*)d_in[5];
  float* out = (float*)d_out;
  const size_t lds_bytes = (size_t)NN * ROWD * sizeof(double);  // 133120
  altdiff_kernel<<<dim3(NB), dim3(256), lds_bytes, stream>>>(Q, q, G, h, A, b, out);
}